// Round 1
// baseline (349.341 us; speedup 1.0000x reference)
//
#include <hip/hip_runtime.h>
#include <math.h>

#define E 128
#define NH 4
#define HD 32
#define LN_EPS 1e-5f

// ---------------- K0: per-batch query precompute (tiny) ----------------
// u[b,h,c] = scale * sum_d qh[h*32+d] * wk[(h*32+d)*E + c]
// qbias[b,h] = scale * sum_d qh[h*32+d] * bk[h*32+d]
__global__ void k0_prep(const int* __restrict__ didx,
                        const float* __restrict__ emb,
                        const float* __restrict__ qpw, const float* __restrict__ qpb,
                        const float* __restrict__ wq, const float* __restrict__ bq,
                        const float* __restrict__ wk, const float* __restrict__ bk,
                        float* __restrict__ u_s, float* __restrict__ qbias, int B)
{
    __shared__ float q_sh[E];
    __shared__ float qh_sh[E];
    const int t = threadIdx.x; // 128 threads
    const float scale = 0.17677669529663687f; // 1/sqrt(32)
    for (int b = 0; b < B; ++b) {
        const float* de = emb + (long)didx[b] * E;
        float acc = qpb[t];
        for (int j = 0; j < E; ++j) acc += qpw[t*E + j] * de[j];
        q_sh[t] = acc;
        __syncthreads();
        float acc2 = bq[t];
        for (int j = 0; j < E; ++j) acc2 += wq[t*E + j] * q_sh[j];
        qh_sh[t] = acc2;
        __syncthreads();
        for (int h = 0; h < NH; ++h) {
            float a = 0.f;
            for (int d = 0; d < HD; ++d) a += qh_sh[h*HD + d] * wk[(h*HD + d)*E + t];
            u_s[(b*NH + h)*E + t] = a * scale;
        }
        if (t < NH) {
            float a = 0.f;
            for (int d = 0; d < HD; ++d) a += qh_sh[t*HD + d] * bk[t*HD + d];
            qbias[b*NH + t] = a * scale;
        }
        __syncthreads();
    }
}

// ---------------- K1: scores[b,h,n] (reads x once, coalesced) ----------------
__global__ void k1_scores(const float* __restrict__ x,
                          const float* __restrict__ u_s,
                          const float* __restrict__ qbias,
                          float* __restrict__ sc, int N)
{
    __shared__ float u_sh[NH][E];
    __shared__ float qb_sh[NH];
    const int b = blockIdx.y;
    const int t = threadIdx.x; // 256
    for (int i = t; i < NH*E; i += 256) u_sh[i / E][i % E] = u_s[b*NH*E + i];
    if (t < NH) qb_sh[t] = qbias[b*NH + t];
    __syncthreads();
    const long n0 = (long)blockIdx.x * 1024 + t * 4;
    const float* xb = x + (long)b * E * N;
    float4 acc[NH];
    for (int h = 0; h < NH; ++h) acc[h] = make_float4(0.f, 0.f, 0.f, 0.f);
    for (int c = 0; c < E; ++c) {
        float4 xv = *(const float4*)(xb + (long)c * N + n0);
        #pragma unroll
        for (int h = 0; h < NH; ++h) {
            float uu = u_sh[h][c];
            acc[h].x += uu * xv.x; acc[h].y += uu * xv.y;
            acc[h].z += uu * xv.z; acc[h].w += uu * xv.w;
        }
    }
    for (int h = 0; h < NH; ++h) {
        float4 r = acc[h];
        float qq = qb_sh[h];
        r.x += qq; r.y += qq; r.z += qq; r.w += qq;
        *(float4*)(sc + (long)(b*NH + h) * N + n0) = r;
    }
}

// ---------------- K2a: per-chunk softmax partials (max, sumexp) ----------------
__global__ void k2a_partial(const float* __restrict__ sc,
                            float* __restrict__ mp, float* __restrict__ lp,
                            int N, int NCH)
{
    __shared__ float red[256];
    const int blk = blockIdx.x;
    const int ch = blk % NCH;
    const int bh = blk / NCH;
    const int t = threadIdx.x;
    const float4* p = (const float4*)(sc + (long)bh * N + (long)ch * 2048);
    float4 v0 = p[t], v1 = p[t + 256];
    float mx = fmaxf(fmaxf(fmaxf(v0.x, v0.y), fmaxf(v0.z, v0.w)),
                     fmaxf(fmaxf(v1.x, v1.y), fmaxf(v1.z, v1.w)));
    red[t] = mx; __syncthreads();
    for (int s = 128; s > 0; s >>= 1) { if (t < s) red[t] = fmaxf(red[t], red[t + s]); __syncthreads(); }
    float bm = red[0];
    __syncthreads();
    float se = expf(v0.x - bm) + expf(v0.y - bm) + expf(v0.z - bm) + expf(v0.w - bm)
             + expf(v1.x - bm) + expf(v1.y - bm) + expf(v1.z - bm) + expf(v1.w - bm);
    red[t] = se; __syncthreads();
    for (int s = 128; s > 0; s >>= 1) { if (t < s) red[t] += red[t + s]; __syncthreads(); }
    if (t == 0) { mp[bh*NCH + ch] = bm; lp[bh*NCH + ch] = red[0]; }
}

// ---------------- K2b: combine partials -> m, 1/l (tiny) ----------------
__global__ void k2b_final(const float* __restrict__ mp, const float* __restrict__ lp,
                          float* __restrict__ m_f, float* __restrict__ invl,
                          int NCH, int BH)
{
    const int t = threadIdx.x;
    if (t < BH) {
        float m = -1e30f;
        for (int i = 0; i < NCH; ++i) m = fmaxf(m, mp[t*NCH + i]);
        float l = 0.f;
        for (int i = 0; i < NCH; ++i) l += lp[t*NCH + i] * expf(mp[t*NCH + i] - m);
        m_f[t] = m;
        invl[t] = 1.f / l;
    }
}

// ---------------- K2c: normalize scores in place -> probabilities ----------------
__global__ void k2c_norm(float* __restrict__ sc,
                         const float* __restrict__ m_f, const float* __restrict__ invl,
                         int N, long total4)
{
    long i = (long)blockIdx.x * blockDim.x + threadIdx.x;
    const long stride = (long)gridDim.x * blockDim.x;
    for (; i < total4; i += stride) {
        long e = i * 4;
        int bh = (int)(e / N);
        float m = m_f[bh], il = invl[bh];
        float4 v = ((float4*)sc)[i];
        v.x = expf(v.x - m) * il;
        v.y = expf(v.y - m) * il;
        v.z = expf(v.z - m) * il;
        v.w = expf(v.w - m) * il;
        ((float4*)sc)[i] = v;
    }
}

// ---------------- K3: s[b,h,c] = sum_n p[b,h,n] * x[b,c,n] (reads x again) ----------------
__global__ void k3_ctx(const float* __restrict__ x, const float* __restrict__ p,
                       float* __restrict__ s_out, int N)
{
    const int c = blockIdx.x;
    const int b = blockIdx.y;
    const int t = threadIdx.x; // 256
    const float4* xb = (const float4*)(x + ((long)b * E + c) * N);
    const float4* p0 = (const float4*)(p + (long)(b*NH + 0) * N);
    const float4* p1 = (const float4*)(p + (long)(b*NH + 1) * N);
    const float4* p2 = (const float4*)(p + (long)(b*NH + 2) * N);
    const float4* p3 = (const float4*)(p + (long)(b*NH + 3) * N);
    float a0 = 0.f, a1 = 0.f, a2 = 0.f, a3 = 0.f;
    const int n4 = N / 4;
    for (int i = t; i < n4; i += 256) {
        float4 xv = xb[i];
        float4 w;
        w = p0[i]; a0 += w.x*xv.x + w.y*xv.y + w.z*xv.z + w.w*xv.w;
        w = p1[i]; a1 += w.x*xv.x + w.y*xv.y + w.z*xv.z + w.w*xv.w;
        w = p2[i]; a2 += w.x*xv.x + w.y*xv.y + w.z*xv.z + w.w*xv.w;
        w = p3[i]; a3 += w.x*xv.x + w.y*xv.y + w.z*xv.z + w.w*xv.w;
    }
    __shared__ float4 red[256];
    red[t] = make_float4(a0, a1, a2, a3);
    __syncthreads();
    for (int s = 128; s > 0; s >>= 1) {
        if (t < s) {
            float4 a = red[t], b2 = red[t + s];
            a.x += b2.x; a.y += b2.y; a.z += b2.z; a.w += b2.w;
            red[t] = a;
        }
        __syncthreads();
    }
    if (t == 0) {
        s_out[(b*NH + 0)*E + c] = red[0].x;
        s_out[(b*NH + 1)*E + c] = red[0].y;
        s_out[(b*NH + 2)*E + c] = red[0].z;
        s_out[(b*NH + 3)*E + c] = red[0].w;
    }
}

// ---------------- K4: ctx -> out -> LayerNorm (tiny, one block per batch) ----------------
__global__ void k4_outln(const float* __restrict__ s, const float* __restrict__ wv,
                         const float* __restrict__ bv, const float* __restrict__ wo,
                         const float* __restrict__ bo, const float* __restrict__ g,
                         const float* __restrict__ bet, float* __restrict__ ln_out)
{
    const int b = blockIdx.x;
    const int t = threadIdx.x; // 128
    __shared__ float s_sh[NH * E];
    __shared__ float ctx_sh[E];
    __shared__ float red[128];
    for (int i = t; i < NH*E; i += 128) s_sh[i] = s[b*NH*E + i];
    __syncthreads();
    const int h = t / HD;
    float a = bv[t];
    for (int c = 0; c < E; ++c) a += wv[t*E + c] * s_sh[h*E + c];
    ctx_sh[t] = a;
    __syncthreads();
    float o = bo[t];
    for (int i = 0; i < E; ++i) o += wo[t*E + i] * ctx_sh[i];
    red[t] = o; __syncthreads();
    for (int st = 64; st > 0; st >>= 1) { if (t < st) red[t] += red[t + st]; __syncthreads(); }
    float mu = red[0] / E;
    __syncthreads();
    float d = o - mu;
    red[t] = d * d; __syncthreads();
    for (int st = 64; st > 0; st >>= 1) { if (t < st) red[t] += red[t + st]; __syncthreads(); }
    float var = red[0] / E;
    ln_out[b*E + t] = d * rsqrtf(var + LN_EPS) * g[t] + bet[t];
}

// ---------------- K5: out = x + ln broadcast (streaming) ----------------
__global__ void k5_resid(const float* __restrict__ x, const float* __restrict__ ln,
                         float* __restrict__ out, int N, long total4)
{
    long i = (long)blockIdx.x * blockDim.x + threadIdx.x;
    const long stride = (long)gridDim.x * blockDim.x;
    for (; i < total4; i += stride) {
        long e = i * 4;
        int bc = (int)(e / N); // b*E + c
        float l = ln[bc];
        float4 v = ((const float4*)x)[i];
        v.x += l; v.y += l; v.z += l; v.w += l;
        ((float4*)out)[i] = v;
    }
}

extern "C" void kernel_launch(void* const* d_in, const int* in_sizes, int n_in,
                              void* d_out, int out_size, void* d_ws, size_t ws_size,
                              hipStream_t stream) {
    const float* x   = (const float*)d_in[0];
    const int*   didx= (const int*)d_in[1];
    const float* emb = (const float*)d_in[2];
    const float* qpw = (const float*)d_in[3];
    const float* qpb = (const float*)d_in[4];
    const float* wq  = (const float*)d_in[5];
    const float* bq  = (const float*)d_in[6];
    const float* wk  = (const float*)d_in[7];
    const float* bk  = (const float*)d_in[8];
    const float* wv  = (const float*)d_in[9];
    const float* bv  = (const float*)d_in[10];
    const float* wo  = (const float*)d_in[11];
    const float* bo  = (const float*)d_in[12];
    const float* lng = (const float*)d_in[13];
    const float* lnb = (const float*)d_in[14];
    float* out = (float*)d_out;

    const int B = in_sizes[1];
    const long totalx = (long)in_sizes[0];
    const int N = (int)(totalx / ((long)B * E)); // 131072
    const int NCH = N / 2048;
    const int BH = B * NH;

    // workspace layout (floats); scores/probs live in d_out (overwritten by K5)
    float* ws    = (float*)d_ws;
    float* u_s   = ws;                    // B*NH*E
    float* qbias = u_s   + B*NH*E;        // B*NH
    float* mp    = qbias + B*NH;          // B*NH*NCH
    float* lp    = mp    + (long)B*NH*NCH;// B*NH*NCH
    float* m_f   = lp    + (long)B*NH*NCH;// B*NH
    float* invl  = m_f   + B*NH;          // B*NH
    float* s_ctx = invl  + B*NH;          // B*NH*E
    float* ln_o  = s_ctx + B*NH*E;        // B*E
    float* sc    = out;                   // B*NH*N scores/probs scratch

    k0_prep<<<1, 128, 0, stream>>>(didx, emb, qpw, qpb, wq, bq, wk, bk, u_s, qbias, B);

    dim3 g1(N / 1024, B);
    k1_scores<<<g1, 256, 0, stream>>>(x, u_s, qbias, sc, N);

    k2a_partial<<<BH * NCH, 256, 0, stream>>>(sc, mp, lp, N, NCH);
    k2b_final<<<1, 64, 0, stream>>>(mp, lp, m_f, invl, NCH, BH);

    long total4sc = (long)BH * N / 4;
    k2c_norm<<<512, 256, 0, stream>>>(sc, m_f, invl, N, total4sc);

    dim3 g3(E, B);
    k3_ctx<<<g3, 256, 0, stream>>>(x, sc, s_ctx, N);

    k4_outln<<<B, 128, 0, stream>>>(s_ctx, wv, bv, wo, bo, lng, lnb, ln_o);

    long total4 = (long)B * E * N / 4;
    k5_resid<<<2048, 256, 0, stream>>>(x, ln_o, out, N, total4);
}

// Round 2
// 332.722 us; speedup vs baseline: 1.0499x; 1.0499x over previous
//
#include <hip/hip_runtime.h>
#include <hip/hip_bf16.h>
#include <math.h>

#define E 128
#define NH 4
#define HD 32
#define LN_EPS 1e-5f

typedef unsigned short ushort_t;
struct ushort4_t { unsigned short x, y, z, w; };

__device__ inline float bf2f(unsigned short u) {
    return __uint_as_float(((unsigned int)u) << 16);
}
__device__ inline unsigned short f2bf(float f) {
    __hip_bfloat16 h = __float2bfloat16(f);
    return *(unsigned short*)&h;
}

// ---------------- K0: per-batch query precompute (tiny) ----------------
__global__ void k0_prep(const int* __restrict__ didx,
                        const float* __restrict__ emb,
                        const float* __restrict__ qpw, const float* __restrict__ qpb,
                        const float* __restrict__ wq, const float* __restrict__ bq,
                        const float* __restrict__ wk, const float* __restrict__ bk,
                        float* __restrict__ u_s, float* __restrict__ qbias, int B)
{
    __shared__ float q_sh[E];
    __shared__ float qh_sh[E];
    const int t = threadIdx.x; // 128 threads
    const float scale = 0.17677669529663687f; // 1/sqrt(32)
    for (int b = 0; b < B; ++b) {
        const float* de = emb + (long)didx[b] * E;
        float acc = qpb[t];
        for (int j = 0; j < E; ++j) acc += qpw[t*E + j] * de[j];
        q_sh[t] = acc;
        __syncthreads();
        float acc2 = bq[t];
        for (int j = 0; j < E; ++j) acc2 += wq[t*E + j] * q_sh[j];
        qh_sh[t] = acc2;
        __syncthreads();
        for (int h = 0; h < NH; ++h) {
            float a = 0.f;
            for (int d = 0; d < HD; ++d) a += qh_sh[h*HD + d] * wk[(h*HD + d)*E + t];
            u_s[(b*NH + h)*E + t] = a * scale;
        }
        if (t < NH) {
            float a = 0.f;
            for (int d = 0; d < HD; ++d) a += qh_sh[t*HD + d] * bk[t*HD + d];
            qbias[b*NH + t] = a * scale;
        }
        __syncthreads();
    }
}

// ---------------- K1: scores + fused per-chunk softmax partials ----------------
// block = (b, chunk of 1024 n). Writes scores to sc, chunk (max, sumexp) to mp/lp.
__global__ void k1_scores(const float* __restrict__ x,
                          const float* __restrict__ u_s,
                          const float* __restrict__ qbias,
                          float* __restrict__ sc,
                          float* __restrict__ mp, float* __restrict__ lp,
                          int N, int NCH)
{
    __shared__ float u_sh[NH][E];
    __shared__ float4 red[256];
    const int b = blockIdx.y;
    const int t = threadIdx.x; // 256
    for (int i = t; i < NH*E; i += 256) u_sh[i >> 7][i & 127] = u_s[b*NH*E + i];
    __syncthreads();
    const long n0 = (long)blockIdx.x * 1024 + t * 4;
    const float* xb = x + (long)b * E * N;
    float4 acc[NH];
    #pragma unroll
    for (int h = 0; h < NH; ++h) acc[h] = make_float4(0.f, 0.f, 0.f, 0.f);
    #pragma unroll 4
    for (int c = 0; c < E; ++c) {
        float4 xv = *(const float4*)(xb + (long)c * N + n0);
        #pragma unroll
        for (int h = 0; h < NH; ++h) {
            float uu = u_sh[h][c];
            acc[h].x += uu * xv.x; acc[h].y += uu * xv.y;
            acc[h].z += uu * xv.z; acc[h].w += uu * xv.w;
        }
    }
    float ml[NH];
    #pragma unroll
    for (int h = 0; h < NH; ++h) {
        float qb = qbias[b*NH + h];
        float4 r = acc[h];
        r.x += qb; r.y += qb; r.z += qb; r.w += qb;
        acc[h] = r;
        *(float4*)(sc + (long)(b*NH + h) * N + n0) = r;
        ml[h] = fmaxf(fmaxf(r.x, r.y), fmaxf(r.z, r.w));
    }
    // block-reduce max per head (packed in float4)
    red[t] = make_float4(ml[0], ml[1], ml[2], ml[3]);
    __syncthreads();
    for (int s = 128; s > 0; s >>= 1) {
        if (t < s) {
            float4 a = red[t], o = red[t + s];
            a.x = fmaxf(a.x, o.x); a.y = fmaxf(a.y, o.y);
            a.z = fmaxf(a.z, o.z); a.w = fmaxf(a.w, o.w);
            red[t] = a;
        }
        __syncthreads();
    }
    float4 bm = red[0];
    __syncthreads();
    float bmv[NH] = {bm.x, bm.y, bm.z, bm.w};
    float ll[NH];
    #pragma unroll
    for (int h = 0; h < NH; ++h) {
        float4 r = acc[h];
        ll[h] = __expf(r.x - bmv[h]) + __expf(r.y - bmv[h])
              + __expf(r.z - bmv[h]) + __expf(r.w - bmv[h]);
    }
    red[t] = make_float4(ll[0], ll[1], ll[2], ll[3]);
    __syncthreads();
    for (int s = 128; s > 0; s >>= 1) {
        if (t < s) {
            float4 a = red[t], o = red[t + s];
            a.x += o.x; a.y += o.y; a.z += o.z; a.w += o.w;
            red[t] = a;
        }
        __syncthreads();
    }
    if (t == 0) {
        float4 ls = red[0];
        const int ch = blockIdx.x;
        mp[(b*NH + 0)*NCH + ch] = bm.x; lp[(b*NH + 0)*NCH + ch] = ls.x;
        mp[(b*NH + 1)*NCH + ch] = bm.y; lp[(b*NH + 1)*NCH + ch] = ls.y;
        mp[(b*NH + 2)*NCH + ch] = bm.z; lp[(b*NH + 2)*NCH + ch] = ls.z;
        mp[(b*NH + 3)*NCH + ch] = bm.w; lp[(b*NH + 3)*NCH + ch] = ls.w;
    }
}

// ---------------- K2b: combine partials + zero ctx accumulator ----------------
__global__ void k2b_final(const float* __restrict__ mp, const float* __restrict__ lp,
                          float* __restrict__ m_f, float* __restrict__ invl,
                          float* __restrict__ s_ctx,
                          int NCH, int BH, int nzero)
{
    const int t = threadIdx.x;
    if (t < BH) {
        float m = -1e30f;
        for (int i = 0; i < NCH; ++i) m = fmaxf(m, mp[t*NCH + i]);
        float l = 0.f;
        for (int i = 0; i < NCH; ++i) l += lp[t*NCH + i] * __expf(mp[t*NCH + i] - m);
        m_f[t] = m;
        invl[t] = 1.f / l;
    }
    for (int i = t; i < nzero; i += blockDim.x) s_ctx[i] = 0.f;
}

// ---------------- K2c: scores -> normalized probabilities (bf16) ----------------
__global__ void k2c_norm(const float* __restrict__ sc,
                         const float* __restrict__ m_f, const float* __restrict__ invl,
                         ushort_t* __restrict__ pb, int sh2, long total4)
{
    long i = (long)blockIdx.x * blockDim.x + threadIdx.x;
    const long stride = (long)gridDim.x * blockDim.x;
    for (; i < total4; i += stride) {
        const int bh = (int)(i >> sh2);
        const float m = m_f[bh], il = invl[bh];
        float4 v = ((const float4*)sc)[i];
        ushort4_t u;
        u.x = f2bf(__expf(v.x - m) * il);
        u.y = f2bf(__expf(v.y - m) * il);
        u.z = f2bf(__expf(v.z - m) * il);
        u.w = f2bf(__expf(v.w - m) * il);
        ((ushort4_t*)pb)[i] = u;
    }
}

// ---------------- K3: ctx partial sums. block = (2 c-rows) x (N/2), coalesced ----------------
__global__ void k3_ctx(const float* __restrict__ x, const ushort_t* __restrict__ pb,
                       float* __restrict__ s_ctx, int N)
{
    __shared__ float4 red[256];
    const int b = blockIdx.z;
    const int half = blockIdx.y;
    const int t = threadIdx.x; // 256
    const int r = t >> 7;        // which of the 2 rows
    const int lane = t & 127;
    const int c = blockIdx.x * 2 + r;
    const long N2 = (long)N >> 1;
    const float4* xr = (const float4*)(x + ((long)b * E + c) * N + half * N2);
    const ushort4_t* p0 = (const ushort4_t*)(pb + ((long)(b*NH + 0)) * N + half * N2);
    const ushort4_t* p1 = (const ushort4_t*)(pb + ((long)(b*NH + 1)) * N + half * N2);
    const ushort4_t* p2 = (const ushort4_t*)(pb + ((long)(b*NH + 2)) * N + half * N2);
    const ushort4_t* p3 = (const ushort4_t*)(pb + ((long)(b*NH + 3)) * N + half * N2);
    float a0 = 0.f, a1 = 0.f, a2 = 0.f, a3 = 0.f;
    const int n4 = (int)(N2 >> 2);
    #pragma unroll 2
    for (int i = lane; i < n4; i += 128) {
        float4 xv = xr[i];
        ushort4_t q0 = p0[i], q1 = p1[i], q2 = p2[i], q3 = p3[i];
        a0 += bf2f(q0.x)*xv.x + bf2f(q0.y)*xv.y + bf2f(q0.z)*xv.z + bf2f(q0.w)*xv.w;
        a1 += bf2f(q1.x)*xv.x + bf2f(q1.y)*xv.y + bf2f(q1.z)*xv.z + bf2f(q1.w)*xv.w;
        a2 += bf2f(q2.x)*xv.x + bf2f(q2.y)*xv.y + bf2f(q2.z)*xv.z + bf2f(q2.w)*xv.w;
        a3 += bf2f(q3.x)*xv.x + bf2f(q3.y)*xv.y + bf2f(q3.z)*xv.z + bf2f(q3.w)*xv.w;
    }
    red[t] = make_float4(a0, a1, a2, a3);
    __syncthreads();
    for (int s = 64; s > 0; s >>= 1) {
        if (lane < s) {
            float4 a = red[t], o = red[t + s];
            a.x += o.x; a.y += o.y; a.z += o.z; a.w += o.w;
            red[t] = a;
        }
        __syncthreads();
    }
    if (lane == 0) {
        float4 a = red[t];
        atomicAdd(&s_ctx[(b*NH + 0)*E + c], a.x);
        atomicAdd(&s_ctx[(b*NH + 1)*E + c], a.y);
        atomicAdd(&s_ctx[(b*NH + 2)*E + c], a.z);
        atomicAdd(&s_ctx[(b*NH + 3)*E + c], a.w);
    }
}

// ---------------- K4: ctx -> out -> LayerNorm (tiny) ----------------
__global__ void k4_outln(const float* __restrict__ s, const float* __restrict__ wv,
                         const float* __restrict__ bv, const float* __restrict__ wo,
                         const float* __restrict__ bo, const float* __restrict__ g,
                         const float* __restrict__ bet, float* __restrict__ ln_out)
{
    const int b = blockIdx.x;
    const int t = threadIdx.x; // 128
    __shared__ float s_sh[NH * E];
    __shared__ float ctx_sh[E];
    __shared__ float red[128];
    for (int i = t; i < NH*E; i += 128) s_sh[i] = s[b*NH*E + i];
    __syncthreads();
    const int h = t / HD;
    float a = bv[t];
    for (int c = 0; c < E; ++c) a += wv[t*E + c] * s_sh[h*E + c];
    ctx_sh[t] = a;
    __syncthreads();
    float o = bo[t];
    for (int i = 0; i < E; ++i) o += wo[t*E + i] * ctx_sh[i];
    red[t] = o; __syncthreads();
    for (int st = 64; st > 0; st >>= 1) { if (t < st) red[t] += red[t + st]; __syncthreads(); }
    float mu = red[0] / E;
    __syncthreads();
    float d = o - mu;
    red[t] = d * d; __syncthreads();
    for (int st = 64; st > 0; st >>= 1) { if (t < st) red[t] += red[t + st]; __syncthreads(); }
    float var = red[0] / E;
    ln_out[b*E + t] = d * rsqrtf(var + LN_EPS) * g[t] + bet[t];
}

// ---------------- K5: out = x + ln broadcast (streaming) ----------------
__global__ void k5_resid(const float* __restrict__ x, const float* __restrict__ ln,
                         float* __restrict__ out, int sh2, long total4)
{
    long i = (long)blockIdx.x * blockDim.x + threadIdx.x;
    const long stride = (long)gridDim.x * blockDim.x;
    for (; i < total4; i += stride) {
        const int bc = (int)(i >> sh2); // b*E + c
        const float l = ln[bc];
        float4 v = ((const float4*)x)[i];
        v.x += l; v.y += l; v.z += l; v.w += l;
        ((float4*)out)[i] = v;
    }
}

extern "C" void kernel_launch(void* const* d_in, const int* in_sizes, int n_in,
                              void* d_out, int out_size, void* d_ws, size_t ws_size,
                              hipStream_t stream) {
    const float* x   = (const float*)d_in[0];
    const int*   didx= (const int*)d_in[1];
    const float* emb = (const float*)d_in[2];
    const float* qpw = (const float*)d_in[3];
    const float* qpb = (const float*)d_in[4];
    const float* wq  = (const float*)d_in[5];
    const float* bq  = (const float*)d_in[6];
    const float* wk  = (const float*)d_in[7];
    const float* bk  = (const float*)d_in[8];
    const float* wv  = (const float*)d_in[9];
    const float* bv  = (const float*)d_in[10];
    const float* wo  = (const float*)d_in[11];
    const float* bo  = (const float*)d_in[12];
    const float* lng = (const float*)d_in[13];
    const float* lnb = (const float*)d_in[14];
    float* out = (float*)d_out;

    const int B = in_sizes[1];
    const long totalx = (long)in_sizes[0];
    const int N = (int)(totalx / ((long)B * E)); // 131072
    const int NCH = N / 1024;
    const int BH = B * NH;
    int lgN = 0; while ((1 << lgN) < N) ++lgN;   // N is a power of two (17)
    const int sh2 = lgN - 2;                     // float4-index -> row index shift

    // workspace layout
    float* ws    = (float*)d_ws;
    float* u_s   = ws;                       // B*NH*E
    float* qbias = u_s   + B*NH*E;           // B*NH
    float* mp    = qbias + B*NH;             // B*NH*NCH
    float* lp    = mp    + (long)B*NH*NCH;   // B*NH*NCH
    float* m_f   = lp    + (long)B*NH*NCH;   // B*NH
    float* invl  = m_f   + B*NH;             // B*NH
    float* s_ctx = invl  + B*NH;             // B*NH*E (atomic accumulator)
    float* ln_o  = s_ctx + B*NH*E;           // B*E
    ushort_t* pb = (ushort_t*)((char*)d_ws + (1 << 16)); // bf16 probs, B*NH*N
    float* sc    = out;                      // raw scores scratch (overwritten by K5)

    k0_prep<<<1, 128, 0, stream>>>(didx, emb, qpw, qpb, wq, bq, wk, bk, u_s, qbias, B);

    dim3 g1(N / 1024, B);
    k1_scores<<<g1, 256, 0, stream>>>(x, u_s, qbias, sc, mp, lp, N, NCH);

    k2b_final<<<1, 256, 0, stream>>>(mp, lp, m_f, invl, s_ctx, NCH, BH, B*NH*E);

    long total4sc = (long)BH * N / 4;
    k2c_norm<<<1024, 256, 0, stream>>>(sc, m_f, invl, pb, sh2, total4sc);

    dim3 g3(E / 2, 2, B);
    k3_ctx<<<g3, 256, 0, stream>>>(x, pb, s_ctx, N);

    k4_outln<<<B, 128, 0, stream>>>(s_ctx, wv, bv, wo, bo, lng, lnb, ln_o);

    long total4 = (long)B * E * N / 4;
    k5_resid<<<2048, 256, 0, stream>>>(x, ln_o, out, sh2, total4);
}